// Round 16
// baseline (272.801 us; speedup 1.0000x reference)
//
#include <hip/hip_runtime.h>

// Tacotron2 decoder — round 16.
// Plateau R9/R14/R15 = 264.3us. lstm_fused<1>=69.5us MfmaUtil 30%: its
//   stage->barrier->compute loop exposes the full vmcnt(0) drain every
//   K-step (no overlap). attn has had stage-ahead since R3.
// R16: lstm_fused v4 — BK=32 double-buffered (2x32KB LDS, same 2 blocks/CU),
//   stage(ks+1) issued BEFORE compute(ks), one barrier/step. Ratio 48 MFMA
//   : 16 ds_read_b128 per wave-step (same 3:1). Swizzle chunk^=(row>>1)&3
//   (2-way, free). Numerics identical (same k order). Rest = R15.

typedef _Float16 f16;
typedef _Float16 f16x8 __attribute__((ext_vector_type(8)));
typedef _Float16 f16x4 __attribute__((ext_vector_type(4)));
typedef float f32x4 __attribute__((ext_vector_type(4)));

constexpr int B_ = 16, T_ = 1024, H_ = 512, M_ = 80;
constexpr int NH_ = 8, D_ = 64;
constexpr int N_ = B_ * T_;  // 16384 rows

#define MFMA16(a, b, c) __builtin_amdgcn_mfma_f32_16x16x32_f16(a, b, c, 0, 0, 0)

__device__ __forceinline__ void gload_lds16(const f16* g, f16* l) {
  __builtin_amdgcn_global_load_lds(
      (const __attribute__((address_space(1))) void*)g,
      (__attribute__((address_space(3))) void*)l, 16, 0, 0);
}

__device__ __forceinline__ float fexp2(float x) {
#if __has_builtin(__builtin_amdgcn_exp2f)
  return __builtin_amdgcn_exp2f(x);
#else
  return exp2f(x);
#endif
}

// ---------------------------------------------------------------------------
// MFMA GEMM body [validated R2-R15]: EPI 0 plain f16, 1 relu f16, 4 fp32.
// ---------------------------------------------------------------------------
template <int EPI, bool CONCATA, bool NCHK>
__device__ __forceinline__ void mgemm_body(
    const f16* __restrict__ A, const f16* __restrict__ A2,
    const f16* __restrict__ Wt, const float* __restrict__ bias,
    const float* __restrict__ bias2, float scale, void* __restrict__ outp,
    int K, int N, int r0, int c0, f16* As, f16* Bs) {
  const int tid = threadIdx.x;
  const int lane = tid & 63, wid = tid >> 6;
  const int lq = lane & 15, lg = lane >> 4;
  const int wm = wid >> 1, wn = wid & 1;

  f32x4 acc[4][4] = {};

  for (int k0 = 0; k0 < K; k0 += 64) {
#pragma unroll
    for (int it = 0; it < 4; ++it) {
      const int off = it * 4096 + wid * 1024 + lane * 16;
      const int row = off >> 7;
      const int cb = (off >> 4) & 7;
      const int kc = k0 + ((cb ^ (row & 7)) << 3);
      const f16* src;
      if (CONCATA) {
        src = (kc < 512) ? (A + (size_t)(r0 + row) * 512 + kc)
                         : (A2 + (size_t)(r0 + row) * 512 + (kc - 512));
      } else {
        src = A + (size_t)(r0 + row) * K + kc;
      }
      gload_lds16(src, (f16*)((char*)As + off));
    }
#pragma unroll
    for (int it = 0; it < 4; ++it) {
      const int off = it * 4096 + wid * 1024 + lane * 16;
      const int row = off >> 7;
      const int cb = (off >> 4) & 7;
      int crow = c0 + row;
      if (NCHK) crow = crow < N ? crow : N - 1;
      gload_lds16(Wt + (size_t)crow * K + k0 + ((cb ^ (row & 7)) << 3),
                  (f16*)((char*)Bs + off));
    }
    __syncthreads();
#pragma unroll
    for (int kk = 0; kk < 2; ++kk) {
      f16x8 af[4], bf[4];
#pragma unroll
      for (int m = 0; m < 4; ++m) {
        const int row = wm * 64 + m * 16 + lq;
        af[m] = *(const f16x8*)((const char*)As + row * 128 +
                                (((kk * 4 + lg) ^ (row & 7)) << 4));
      }
#pragma unroll
      for (int n = 0; n < 4; ++n) {
        const int row = wn * 64 + n * 16 + lq;
        bf[n] = *(const f16x8*)((const char*)Bs + row * 128 +
                                (((kk * 4 + lg) ^ (row & 7)) << 4));
      }
#pragma unroll
      for (int m = 0; m < 4; ++m)
#pragma unroll
        for (int n = 0; n < 4; ++n) acc[m][n] = MFMA16(af[m], bf[n], acc[m][n]);
    }
    __syncthreads();
  }

#pragma unroll
  for (int m = 0; m < 4; ++m) {
    const int rbase = r0 + wm * 64 + m * 16 + lg * 4;
#pragma unroll
    for (int n = 0; n < 4; ++n) {
      const int col = c0 + wn * 64 + n * 16 + lq;
      if (NCHK && col >= N) continue;
      const float bsum = bias[col] + (bias2 ? bias2[col] : 0.f);
      const f32x4 a = acc[m][n];
#pragma unroll
      for (int r = 0; r < 4; ++r) {
        const int row = rbase + r;
        float v = (a[r] + bsum) * scale;
        if (EPI == 1) v = fmaxf(v, 0.f);
        if (EPI == 4)
          ((float*)outp)[(size_t)row * N + col] = v;
        else
          ((f16*)outp)[(size_t)row * N + col] = (f16)v;
      }
    }
  }
}

template <int EPI, bool CONCATA, bool NCHK>
__global__ __launch_bounds__(256) void mgemm(
    const f16* __restrict__ A, const f16* __restrict__ A2,
    const f16* __restrict__ Wt, const float* __restrict__ bias,
    const float* __restrict__ bias2, float scale, void* __restrict__ outp,
    int K, int N) {
  __shared__ f16 As[128 * 64];
  __shared__ f16 Bs[128 * 64];
  mgemm_body<EPI, CONCATA, NCHK>(A, A2, Wt, bias, bias2, scale, outp, K, N,
                                 blockIdx.x * 128, blockIdx.y * 128, As, Bs);
}

// ---------------------------------------------------------------------------
// kv body [validated R6-R15]
// ---------------------------------------------------------------------------
__device__ __forceinline__ void kv_body(const f16* __restrict__ A,
                                        const f16* __restrict__ Wt,
                                        const float* __restrict__ bias,
                                        f16* __restrict__ kout,
                                        f16* __restrict__ vout, int r0, int c0,
                                        f16* As, f16 (*Bs)[128 * 64]) {
  constexpr int K = 512;
  const int tid = threadIdx.x;
  const int lane = tid & 63, wid = tid >> 6;
  const int lq = lane & 15, lg = lane >> 4;
  const int wm = wid >> 1, wn = wid & 1;

  f32x4 acc[2][4][4] = {};

  for (int k0 = 0; k0 < K; k0 += 64) {
#pragma unroll
    for (int it = 0; it < 4; ++it) {
      const int off = it * 4096 + tid * 16;
      const int row = off >> 7;
      const int cb = (off >> 4) & 7;
      const int kc = k0 + ((cb ^ (row & 7)) << 3);
      gload_lds16(A + (size_t)(r0 + row) * K + kc, (f16*)((char*)As + off));
    }
#pragma unroll
    for (int g = 0; g < 2; ++g) {
#pragma unroll
      for (int it = 0; it < 4; ++it) {
        const int off = it * 4096 + tid * 16;
        const int row = off >> 7;
        const int cb = (off >> 4) & 7;
        gload_lds16(
            Wt + (size_t)(g * 512 + c0 + row) * K + k0 + ((cb ^ (row & 7)) << 3),
            (f16*)((char*)&Bs[g][0] + off));
      }
    }
    __syncthreads();
#pragma unroll
    for (int kk = 0; kk < 2; ++kk) {
      f16x8 af[4];
#pragma unroll
      for (int m = 0; m < 4; ++m) {
        const int row = wm * 64 + m * 16 + lq;
        af[m] = *(const f16x8*)((const char*)As + row * 128 +
                                (((kk * 4 + lg) ^ (row & 7)) << 4));
      }
#pragma unroll
      for (int g = 0; g < 2; ++g)
#pragma unroll
        for (int n = 0; n < 4; ++n) {
          const int row = wn * 64 + n * 16 + lq;
          const f16x8 bf = *(const f16x8*)((const char*)&Bs[g][0] + row * 128 +
                                           (((kk * 4 + lg) ^ (row & 7)) << 4));
#pragma unroll
          for (int m = 0; m < 4; ++m)
            acc[g][m][n] = MFMA16(af[m], bf, acc[g][m][n]);
        }
    }
    __syncthreads();
  }

#pragma unroll
  for (int m = 0; m < 4; ++m) {
    const int rbase = r0 + wm * 64 + m * 16 + lg * 4;
    const int b = rbase >> 10, t = rbase & (T_ - 1);
#pragma unroll
    for (int n = 0; n < 4; ++n) {
      const int col = c0 + wn * 64 + n * 16 + lq;
      const float bk = bias[col];
#pragma unroll
      for (int r = 0; r < 4; ++r)
        kout[(size_t)(rbase + r) * 512 + col] = (f16)(acc[0][m][n][r] + bk);
      const float bv = bias[512 + col];
      const int head = col >> 6, d = col & 63;
      f16x4 pk;
#pragma unroll
      for (int r = 0; r < 4; ++r) pk[r] = (f16)(acc[1][m][n][r] + bv);
      *(f16x4*)(vout + ((size_t)((b * NH_ + head) * D_ + d)) * T_ + t) = pk;
    }
  }
}

// prenet (even bids) || kv projection (odd bids) [validated R14/R15]
__global__ __launch_bounds__(256, 2) void prenet_kv(
    const f16* __restrict__ PM, const f16* __restrict__ WP,
    const float* __restrict__ bpre, f16* __restrict__ pre,
    const f16* __restrict__ EncB, const f16* __restrict__ Wkv,
    const float* __restrict__ bkv, f16* __restrict__ kout,
    f16* __restrict__ vout) {
  __shared__ f16 As[128 * 64];
  __shared__ f16 Bs[2][128 * 64];
  const int bid = blockIdx.x;
  const int f = bid >> 1;
  const int r0 = (f >> 2) * 128, c0 = (f & 3) * 128;
  if (bid & 1) {
    kv_body(EncB, Wkv, bkv, kout, vout, r0, c0, As, Bs);
  } else {
    mgemm_body<1, false, false>(PM, nullptr, WP, bpre, nullptr, 1.f, pre, 128,
                                512, r0, c0, As, &Bs[0][0]);
  }
}

// ---------------------------------------------------------------------------
// Fused zero-state LSTM v4 — BK=32, double-buffered, stage-ahead pipeline.
// LDS: 2 x (A 8KB + 3xB 8KB) = 64KB (2 blocks/CU, same as v3).
// Swizzle: 64B rows, chunk ^= (row>>1)&3 -> read banks 2-way (free).
// Accumulation order over k identical to v3 (ascending). Epilogue unchanged.
// ---------------------------------------------------------------------------
template <bool CONCATA>
__global__ __launch_bounds__(256, 2) void lstm_fused(
    const f16* __restrict__ A, const f16* __restrict__ A2,
    const f16* __restrict__ Wih, const float* __restrict__ bih,
    const float* __restrict__ bhh, f16* __restrict__ Hout_) {
  constexpr int K = CONCATA ? 1024 : 512;
  constexpr int NS = K / 32;
  __shared__ f16 As[2][128 * 32];
  __shared__ f16 Bs[2][3][128 * 32];
  const int tid = threadIdx.x;
  const int lane = tid & 63, wid = tid >> 6;
  const int lq = lane & 15, lg = lane >> 4;
  const int wm = wid >> 1, wn = wid & 1;
  const int r0 = blockIdx.x * 128, c0 = blockIdx.y * 128;

  f32x4 acc[3][4][4] = {};

  auto stage = [&](int ks, int buf) {
#pragma unroll
    for (int it = 0; it < 2; ++it) {
      const int off = it * 4096 + tid * 16;  // byte offset in 8KB tile
      const int row = off >> 6;              // 64B rows
      const int cb = (off >> 4) & 3;
      const int kc = ks * 32 + ((cb ^ ((row >> 1) & 3)) << 3);
      const f16* src;
      if (CONCATA) {
        src = (kc < 512) ? (A + (size_t)(r0 + row) * 512 + kc)
                         : (A2 + (size_t)(r0 + row) * 512 + (kc - 512));
      } else {
        src = A + (size_t)(r0 + row) * K + kc;
      }
      gload_lds16(src, (f16*)((char*)&As[buf][0] + off));
    }
#pragma unroll
    for (int g = 0; g < 3; ++g) {
      const int gbase = (g == 0) ? 0 : 512 * (g + 1);  // i=0, g=1024, o=1536
#pragma unroll
      for (int it = 0; it < 2; ++it) {
        const int off = it * 4096 + tid * 16;
        const int row = off >> 6;
        const int cb = (off >> 4) & 3;
        const int kc = ks * 32 + ((cb ^ ((row >> 1) & 3)) << 3);
        gload_lds16(Wih + (size_t)(gbase + c0 + row) * K + kc,
                    (f16*)((char*)&Bs[buf][g][0] + off));
      }
    }
  };

  stage(0, 0);
  __syncthreads();

  for (int ks = 0; ks < NS; ++ks) {
    const int cur = ks & 1;
    if (ks + 1 < NS) stage(ks + 1, cur ^ 1);  // overlap with compute below

    f16x8 af[4];
#pragma unroll
    for (int m = 0; m < 4; ++m) {
      const int row = wm * 64 + m * 16 + lq;
      af[m] = *(const f16x8*)((const char*)&As[cur][0] + row * 64 +
                              ((lg ^ ((row >> 1) & 3)) << 4));
    }
#pragma unroll
    for (int g = 0; g < 3; ++g)
#pragma unroll
      for (int n = 0; n < 4; ++n) {
        const int row = wn * 64 + n * 16 + lq;
        const f16x8 bf =
            *(const f16x8*)((const char*)&Bs[cur][g][0] + row * 64 +
                            ((lg ^ ((row >> 1) & 3)) << 4));
#pragma unroll
        for (int m = 0; m < 4; ++m)
          acc[g][m][n] = MFMA16(af[m], bf, acc[g][m][n]);
      }
    __syncthreads();  // drains stage(ks+1) (hidden under MFMAs) + LDS reuse
  }

#pragma unroll
  for (int n = 0; n < 4; ++n) {
    const int c = c0 + wn * 64 + n * 16 + lq;
    const float bi = bih[c] + bhh[c];
    const float bg = bih[1024 + c] + bhh[1024 + c];
    const float bo = bih[1536 + c] + bhh[1536 + c];
#pragma unroll
    for (int m = 0; m < 4; ++m) {
      const int rbase = r0 + wm * 64 + m * 16 + lg * 4;
#pragma unroll
      for (int r = 0; r < 4; ++r) {
        const float gi = acc[0][m][n][r] + bi;
        const float gg = acc[1][m][n][r] + bg;
        const float go = acc[2][m][n][r] + bo;
        const float si = 1.f / (1.f + __expf(-gi));
        const float so = 1.f / (1.f + __expf(-go));
        const float tg = 2.f / (1.f + __expf(-2.f * gg)) - 1.f;
        const float cc = si * tg;
        const float tc = 2.f / (1.f + __expf(-2.f * cc)) - 1.f;
        Hout_[(size_t)(rbase + r) * 512 + c] = (f16)(so * tc);
      }
    }
  }
}

// ---------------------------------------------------------------------------
// Flash attention v7 [validated R15, unchanged]
// ---------------------------------------------------------------------------
__global__ __launch_bounds__(256, 4) void attn_mfma7(
    const f16* __restrict__ q, const f16* __restrict__ k,
    const f16* __restrict__ vT, f16* __restrict__ ctx) {
  __shared__ f16 Ks[2][64 * 64];
  __shared__ f16 Vs[2][64 * 64];
  __shared__ f16 Ps[4][16 * 64];
  const int bid = blockIdx.x;
  const int nid = (bid & 7) * 128 + (bid >> 3);
  const int qt = nid & 7, bh = nid >> 3;
  const int head = bh & 7, b = bh >> 3;
  const int tid = threadIdx.x, lane = tid & 63, wid = tid >> 6;
  const int lq = lane & 15, lg = lane >> 4;

  const f16* kbase = k + ((size_t)b * T_) * H_ + head * D_;
  const f16* vbase = vT + (size_t)bh * D_ * T_;

  auto stage = [&](int kt, int buf) {
#pragma unroll
    for (int it = 0; it < 2; ++it) {
      const int off = it * 4096 + tid * 16;
      const int row = off >> 7;
      const int sc = ((((off >> 4) & 7) ^ (row & 7)) << 3);
      gload_lds16(kbase + (size_t)(kt * 64 + row) * H_ + sc,
                  (f16*)((char*)&Ks[buf][0] + off));
      gload_lds16(vbase + (size_t)row * T_ + kt * 64 + sc,
                  (f16*)((char*)&Vs[buf][0] + off));
    }
  };

  const int q0 = qt * 128 + wid * 32;
  f16x8 qf[2][2];
#pragma unroll
  for (int s = 0; s < 2; ++s)
#pragma unroll
    for (int kk = 0; kk < 2; ++kk)
      qf[s][kk] = *(const f16x8*)(q + ((size_t)(b * T_) + q0 + s * 16 + lq) * H_ +
                                  head * D_ + kk * 32 + lg * 8);

  f16x8 ones;
#pragma unroll
  for (int j = 0; j < 8; ++j) ones[j] = (f16)1.f;

  f32x4 accO[2][4] = {};
  f32x4 accL[2] = {};
  char* pw = (char*)&Ps[wid][0] + lq * 128;
  const int psw = (lq & 7) << 4;

  stage(0, 0);
  __syncthreads();

  for (int kt = 0; kt < T_ / 64; ++kt) {
    const int cur = kt & 1;
    if (kt < T_ / 64 - 1) stage(kt + 1, cur ^ 1);

    f16x8 kf[4][2];
#pragma unroll
    for (int n = 0; n < 4; ++n)
#pragma unroll
      for (int kk = 0; kk < 2; ++kk) {
        const int row = n * 16 + lq;
        kf[n][kk] = *(const f16x8*)((const char*)&Ks[cur][0] + row * 128 +
                                    (((kk * 4 + lg) ^ (row & 7)) << 4));
      }

#pragma unroll
    for (int s = 0; s < 2; ++s) {
      f32x4 ssw[4] = {};
      __builtin_amdgcn_s_setprio(1);
#pragma unroll
      for (int n = 0; n < 4; ++n)
#pragma unroll
        for (int kk = 0; kk < 2; ++kk)
          ssw[n] = MFMA16(kf[n][kk], qf[s][kk], ssw[n]);
      __builtin_amdgcn_s_setprio(0);

#pragma unroll
      for (int n = 0; n < 4; ++n) {
        f16x4 pk;
#pragma unroll
        for (int r = 0; r < 4; ++r) pk[r] = (f16)fexp2(ssw[n][r]);
        *(f16x4*)(pw + ((n * 32 + lg * 8) ^ psw)) = pk;
      }
      f16x8 pb[2];
#pragma unroll
      for (int kk = 0; kk < 2; ++kk)
        pb[kk] = *(const f16x8*)(pw + ((((kk * 4 + lg) << 4)) ^ psw));

      __builtin_amdgcn_s_setprio(1);
#pragma unroll
      for (int kk = 0; kk < 2; ++kk)
        accL[s] = MFMA16(ones, pb[kk], accL[s]);
#pragma unroll
      for (int n = 0; n < 4; ++n) {
        const int row = n * 16 + lq;
#pragma unroll
        for (int kk = 0; kk < 2; ++kk) {
          const f16x8 vf =
              *(const f16x8*)((const char*)&Vs[cur][0] + row * 128 +
                              (((kk * 4 + lg) ^ (row & 7)) << 4));
          accO[s][n] = MFMA16(vf, pb[kk], accO[s][n]);
        }
      }
      __builtin_amdgcn_s_setprio(0);
    }
    __syncthreads();
  }

#pragma unroll
  for (int s = 0; s < 2; ++s) {
    const float inv = 1.f / accL[s][0];
    const size_t rowoff = ((size_t)(b * T_) + q0 + s * 16 + lq) * H_ + head * D_;
#pragma unroll
    for (int n = 0; n < 4; ++n) {
      f16x4 o;
#pragma unroll
      for (int r = 0; r < 4; ++r) o[r] = (f16)(accO[s][n][r] * inv);
      *(f16x4*)(ctx + rowoff + n * 16 + lg * 4) = o;
    }
  }
}

// ---------------------------------------------------------------------------
// Merged conversions + builders [validated R7-R15, unchanged]
// ---------------------------------------------------------------------------
constexpr int C0 = 2097152;            // enc
constexpr int C1 = C0 + 196608;        // inw
constexpr int C2 = C1 + 65536;         // outw
constexpr int C3 = C2 + 524288;        // wih0
constexpr int C4 = C3 + 262144;        // wih1
constexpr int C5 = C4 + 10240;         // wmel
constexpr int C6 = C5 + 524288;        // pm
constexpr int C7 = C6 + 16384;         // wp
__global__ void conv_all(const float* __restrict__ enc, const float* __restrict__ inw,
                         const float* __restrict__ outw, const float* __restrict__ wih0,
                         const float* __restrict__ wih1, const float* __restrict__ wmel,
                         const float* __restrict__ tmel, const float* __restrict__ wpre,
                         f16* denc, f16* dinw, f16* doutw, f16* dwih0,
                         f16* dwih1, f16* dwmel, f16* dpm, f16* dwp) {
  const int i = blockIdx.x * blockDim.x + threadIdx.x;
  if (i >= C7) return;
  if (i < C5) {
    const float* s;
    f16* d;
    int off;
    if (i < C0) { s = enc; d = denc; off = i; }
    else if (i < C1) { s = inw; d = dinw; off = i - C0; }
    else if (i < C2) { s = outw; d = doutw; off = i - C1; }
    else if (i < C3) { s = wih0; d = dwih0; off = i - C2; }
    else if (i < C4) { s = wih1; d = dwih1; off = i - C3; }
    else { s = wmel; d = dwmel; off = i - C4; }
    const float4 v = ((const float4*)s)[off];
    f16x4 o = {(f16)v.x, (f16)v.y, (f16)v.z, (f16)v.w};
    ((f16x4*)d)[off] = o;
  } else if (i < C6) {
    const int j = i - C5;
    const int r = j >> 5, c4 = (j & 31) * 4;
    const int t = r & (T_ - 1);
    f16x4 o = {};
    if (t != 0 && c4 < M_) {
      const float4 v = *(const float4*)(tmel + (size_t)(r - 1) * M_ + c4);
      o = {(f16)v.x, (f16)v.y, (f16)v.z, (f16)v.w};
    }
    *(f16x4*)(dpm + (size_t)r * 128 + c4) = o;
  } else {
    const int j = i - C6;
    const int r = j >> 5, c4 = (j & 31) * 4;
    f16x4 o = {};
    if (c4 < M_) {
      const float4 v = *(const float4*)(wpre + (size_t)r * M_ + c4);
      o = {(f16)v.x, (f16)v.y, (f16)v.z, (f16)v.w};
    }
    *(f16x4*)(dwp + (size_t)r * 128 + c4) = o;
  }
}

// ---------------------------------------------------------------------------
extern "C" void kernel_launch(void* const* d_in, const int* in_sizes, int n_in,
                              void* d_out, int out_size, void* d_ws,
                              size_t ws_size, hipStream_t stream) {
  const float* enc = (const float*)d_in[0];
  const float* tmel = (const float*)d_in[1];
  const float* w_pre = (const float*)d_in[2];
  const float* b_pre = (const float*)d_in[3];
  const float* inw = (const float*)d_in[4];
  const float* inb = (const float*)d_in[5];
  const float* outw = (const float*)d_in[6];
  const float* outb = (const float*)d_in[7];
  const float* wih0 = (const float*)d_in[8];
  const float* bih0 = (const float*)d_in[10];
  const float* bhh0 = (const float*)d_in[11];
  const float* wih1 = (const float*)d_in[12];
  const float* bih1 = (const float*)d_in[14];
  const float* bhh1 = (const float*)d_in[15];
  const float* wmel = (const float*)d_in[16];
  const float* bmel = (const float*)d_in[17];

  f16* wsh = (f16*)d_ws;
  const size_t SEG = (size_t)N_ * H_;
  f16* EncB = wsh;                     // S0; reused as aout
  f16* h1 = wsh + SEG;                 // S1
  f16* pre = wsh + 2 * SEG;            // S2
  f16* qb = wsh + 3 * SEG;             // S3; reused as h2
  f16* kbuf = wsh + 4 * SEG;           // S4
  f16* vTb = wsh + 5 * SEG;            // S5
  f16* ctx = wsh + 6 * SEG;            // S6
  f16* aout = EncB;
  f16* h2 = qb;
  f16* WP = wsh + 7 * SEG;
  f16* WIN = WP + 512 * 128;
  f16* WOUT = WIN + 1536 * 512;
  f16* WIH0 = WOUT + 512 * 512;
  f16* WIH1 = WIH0 + (size_t)2048 * 1024;
  f16* WMEL = WIH1 + 2048 * 512;
  f16* PM = WMEL + 80 * 512;

  const dim3 blk(256);
  conv_all<<<(C7 + 255) / 256, blk, 0, stream>>>(
      enc, inw, outw, wih0, wih1, wmel, tmel, w_pre, EncB, WIN, WOUT, WIH0,
      WIH1, WMEL, PM, WP);

  // prenet || kv projection
  prenet_kv<<<dim3(1024), blk, 0, stream>>>(PM, WP, b_pre, pre, EncB,
                                            WIN + 512 * 512, inb + 512, kbuf,
                                            vTb);

  const dim3 g512(N_ / 128, 4), g80(N_ / 128, 1);
  // q pre-scaled by log2e / sqrt(64) -> softmax runs in exp2 domain
  mgemm<0, false, false><<<g512, blk, 0, stream>>>(
      pre, nullptr, WIN, inb, nullptr, 0.125f * 1.44269504088896f, qb, 512, 512);
  attn_mfma7<<<dim3(1024), blk, 0, stream>>>(qb, kbuf, vTb, ctx);
  mgemm<0, false, false><<<g512, blk, 0, stream>>>(ctx, nullptr, WOUT, outb,
                                                   nullptr, 1.f, aout, 512, 512);
  lstm_fused<true><<<g512, blk, 0, stream>>>(pre, aout, WIH0, bih0, bhh0, h1);
  lstm_fused<false><<<g512, blk, 0, stream>>>(h1, nullptr, WIH1, bih1, bhh1, h2);
  mgemm<4, false, true><<<g80, blk, 0, stream>>>(h2, nullptr, WMEL, bmel,
                                                 nullptr, 1.f, (float*)d_out,
                                                 512, 80);
}

// Round 17
// 264.157 us; speedup vs baseline: 1.0327x; 1.0327x over previous
//
#include <hip/hip_runtime.h>

// Tacotron2 decoder — round 17 (revert to best-known).
// R1 2647 -> R2 512 -> R3 364 -> R5 308 -> R6 285.7 -> R9 264.3 (plateau,
//   reproduced R14/R15). R16 lstm-dbuf REGRESSED 69.5->75.2us, confirming
//   the guide's m99/m100 finding: source-level dbuf on the 2-barrier
//   structure is the ceiling, implicit wave overlap already captures it.
// R17: exact R15 config (R9 lstm / attn v7 / prenet||kv). All hot kernels
//   at their validated-best form. If this lands ~264.3, declare ceiling.

typedef _Float16 f16;
typedef _Float16 f16x8 __attribute__((ext_vector_type(8)));
typedef _Float16 f16x4 __attribute__((ext_vector_type(4)));
typedef float f32x4 __attribute__((ext_vector_type(4)));

constexpr int B_ = 16, T_ = 1024, H_ = 512, M_ = 80;
constexpr int NH_ = 8, D_ = 64;
constexpr int N_ = B_ * T_;  // 16384 rows

#define MFMA16(a, b, c) __builtin_amdgcn_mfma_f32_16x16x32_f16(a, b, c, 0, 0, 0)

__device__ __forceinline__ void gload_lds16(const f16* g, f16* l) {
  __builtin_amdgcn_global_load_lds(
      (const __attribute__((address_space(1))) void*)g,
      (__attribute__((address_space(3))) void*)l, 16, 0, 0);
}

__device__ __forceinline__ float fexp2(float x) {
#if __has_builtin(__builtin_amdgcn_exp2f)
  return __builtin_amdgcn_exp2f(x);
#else
  return exp2f(x);
#endif
}

// ---------------------------------------------------------------------------
// MFMA GEMM body [validated R2-R15]: EPI 0 plain f16, 1 relu f16, 4 fp32.
// ---------------------------------------------------------------------------
template <int EPI, bool CONCATA, bool NCHK>
__device__ __forceinline__ void mgemm_body(
    const f16* __restrict__ A, const f16* __restrict__ A2,
    const f16* __restrict__ Wt, const float* __restrict__ bias,
    const float* __restrict__ bias2, float scale, void* __restrict__ outp,
    int K, int N, int r0, int c0, f16* As, f16* Bs) {
  const int tid = threadIdx.x;
  const int lane = tid & 63, wid = tid >> 6;
  const int lq = lane & 15, lg = lane >> 4;
  const int wm = wid >> 1, wn = wid & 1;

  f32x4 acc[4][4] = {};

  for (int k0 = 0; k0 < K; k0 += 64) {
#pragma unroll
    for (int it = 0; it < 4; ++it) {
      const int off = it * 4096 + wid * 1024 + lane * 16;
      const int row = off >> 7;
      const int cb = (off >> 4) & 7;
      const int kc = k0 + ((cb ^ (row & 7)) << 3);
      const f16* src;
      if (CONCATA) {
        src = (kc < 512) ? (A + (size_t)(r0 + row) * 512 + kc)
                         : (A2 + (size_t)(r0 + row) * 512 + (kc - 512));
      } else {
        src = A + (size_t)(r0 + row) * K + kc;
      }
      gload_lds16(src, (f16*)((char*)As + off));
    }
#pragma unroll
    for (int it = 0; it < 4; ++it) {
      const int off = it * 4096 + wid * 1024 + lane * 16;
      const int row = off >> 7;
      const int cb = (off >> 4) & 7;
      int crow = c0 + row;
      if (NCHK) crow = crow < N ? crow : N - 1;
      gload_lds16(Wt + (size_t)crow * K + k0 + ((cb ^ (row & 7)) << 3),
                  (f16*)((char*)Bs + off));
    }
    __syncthreads();
#pragma unroll
    for (int kk = 0; kk < 2; ++kk) {
      f16x8 af[4], bf[4];
#pragma unroll
      for (int m = 0; m < 4; ++m) {
        const int row = wm * 64 + m * 16 + lq;
        af[m] = *(const f16x8*)((const char*)As + row * 128 +
                                (((kk * 4 + lg) ^ (row & 7)) << 4));
      }
#pragma unroll
      for (int n = 0; n < 4; ++n) {
        const int row = wn * 64 + n * 16 + lq;
        bf[n] = *(const f16x8*)((const char*)Bs + row * 128 +
                                (((kk * 4 + lg) ^ (row & 7)) << 4));
      }
#pragma unroll
      for (int m = 0; m < 4; ++m)
#pragma unroll
        for (int n = 0; n < 4; ++n) acc[m][n] = MFMA16(af[m], bf[n], acc[m][n]);
    }
    __syncthreads();
  }

#pragma unroll
  for (int m = 0; m < 4; ++m) {
    const int rbase = r0 + wm * 64 + m * 16 + lg * 4;
#pragma unroll
    for (int n = 0; n < 4; ++n) {
      const int col = c0 + wn * 64 + n * 16 + lq;
      if (NCHK && col >= N) continue;
      const float bsum = bias[col] + (bias2 ? bias2[col] : 0.f);
      const f32x4 a = acc[m][n];
#pragma unroll
      for (int r = 0; r < 4; ++r) {
        const int row = rbase + r;
        float v = (a[r] + bsum) * scale;
        if (EPI == 1) v = fmaxf(v, 0.f);
        if (EPI == 4)
          ((float*)outp)[(size_t)row * N + col] = v;
        else
          ((f16*)outp)[(size_t)row * N + col] = (f16)v;
      }
    }
  }
}

template <int EPI, bool CONCATA, bool NCHK>
__global__ __launch_bounds__(256) void mgemm(
    const f16* __restrict__ A, const f16* __restrict__ A2,
    const f16* __restrict__ Wt, const float* __restrict__ bias,
    const float* __restrict__ bias2, float scale, void* __restrict__ outp,
    int K, int N) {
  __shared__ f16 As[128 * 64];
  __shared__ f16 Bs[128 * 64];
  mgemm_body<EPI, CONCATA, NCHK>(A, A2, Wt, bias, bias2, scale, outp, K, N,
                                 blockIdx.x * 128, blockIdx.y * 128, As, Bs);
}

// ---------------------------------------------------------------------------
// kv body [validated R6-R15]
// ---------------------------------------------------------------------------
__device__ __forceinline__ void kv_body(const f16* __restrict__ A,
                                        const f16* __restrict__ Wt,
                                        const float* __restrict__ bias,
                                        f16* __restrict__ kout,
                                        f16* __restrict__ vout, int r0, int c0,
                                        f16* As, f16 (*Bs)[128 * 64]) {
  constexpr int K = 512;
  const int tid = threadIdx.x;
  const int lane = tid & 63, wid = tid >> 6;
  const int lq = lane & 15, lg = lane >> 4;
  const int wm = wid >> 1, wn = wid & 1;

  f32x4 acc[2][4][4] = {};

  for (int k0 = 0; k0 < K; k0 += 64) {
#pragma unroll
    for (int it = 0; it < 4; ++it) {
      const int off = it * 4096 + tid * 16;
      const int row = off >> 7;
      const int cb = (off >> 4) & 7;
      const int kc = k0 + ((cb ^ (row & 7)) << 3);
      gload_lds16(A + (size_t)(r0 + row) * K + kc, (f16*)((char*)As + off));
    }
#pragma unroll
    for (int g = 0; g < 2; ++g) {
#pragma unroll
      for (int it = 0; it < 4; ++it) {
        const int off = it * 4096 + tid * 16;
        const int row = off >> 7;
        const int cb = (off >> 4) & 7;
        gload_lds16(
            Wt + (size_t)(g * 512 + c0 + row) * K + k0 + ((cb ^ (row & 7)) << 3),
            (f16*)((char*)&Bs[g][0] + off));
      }
    }
    __syncthreads();
#pragma unroll
    for (int kk = 0; kk < 2; ++kk) {
      f16x8 af[4];
#pragma unroll
      for (int m = 0; m < 4; ++m) {
        const int row = wm * 64 + m * 16 + lq;
        af[m] = *(const f16x8*)((const char*)As + row * 128 +
                                (((kk * 4 + lg) ^ (row & 7)) << 4));
      }
#pragma unroll
      for (int g = 0; g < 2; ++g)
#pragma unroll
        for (int n = 0; n < 4; ++n) {
          const int row = wn * 64 + n * 16 + lq;
          const f16x8 bf = *(const f16x8*)((const char*)&Bs[g][0] + row * 128 +
                                           (((kk * 4 + lg) ^ (row & 7)) << 4));
#pragma unroll
          for (int m = 0; m < 4; ++m)
            acc[g][m][n] = MFMA16(af[m], bf, acc[g][m][n]);
        }
    }
    __syncthreads();
  }

#pragma unroll
  for (int m = 0; m < 4; ++m) {
    const int rbase = r0 + wm * 64 + m * 16 + lg * 4;
    const int b = rbase >> 10, t = rbase & (T_ - 1);
#pragma unroll
    for (int n = 0; n < 4; ++n) {
      const int col = c0 + wn * 64 + n * 16 + lq;
      const float bk = bias[col];
#pragma unroll
      for (int r = 0; r < 4; ++r)
        kout[(size_t)(rbase + r) * 512 + col] = (f16)(acc[0][m][n][r] + bk);
      const float bv = bias[512 + col];
      const int head = col >> 6, d = col & 63;
      f16x4 pk;
#pragma unroll
      for (int r = 0; r < 4; ++r) pk[r] = (f16)(acc[1][m][n][r] + bv);
      *(f16x4*)(vout + ((size_t)((b * NH_ + head) * D_ + d)) * T_ + t) = pk;
    }
  }
}

// prenet (even bids) || kv projection (odd bids) [validated R14/R15]
__global__ __launch_bounds__(256, 2) void prenet_kv(
    const f16* __restrict__ PM, const f16* __restrict__ WP,
    const float* __restrict__ bpre, f16* __restrict__ pre,
    const f16* __restrict__ EncB, const f16* __restrict__ Wkv,
    const float* __restrict__ bkv, f16* __restrict__ kout,
    f16* __restrict__ vout) {
  __shared__ f16 As[128 * 64];
  __shared__ f16 Bs[2][128 * 64];
  const int bid = blockIdx.x;
  const int f = bid >> 1;
  const int r0 = (f >> 2) * 128, c0 = (f & 3) * 128;
  if (bid & 1) {
    kv_body(EncB, Wkv, bkv, kout, vout, r0, c0, As, Bs);
  } else {
    mgemm_body<1, false, false>(PM, nullptr, WP, bpre, nullptr, 1.f, pre, 128,
                                512, r0, c0, As, &Bs[0][0]);
  }
}

// ---------------------------------------------------------------------------
// Fused zero-state LSTM [EXACT R9 hot loop — validated best, 69.4us @742TF]
// ---------------------------------------------------------------------------
template <bool CONCATA>
__global__ __launch_bounds__(256, 2) void lstm_fused(
    const f16* __restrict__ A, const f16* __restrict__ A2,
    const f16* __restrict__ Wih, const float* __restrict__ bih,
    const float* __restrict__ bhh, f16* __restrict__ Hout_) {
  constexpr int K = CONCATA ? 1024 : 512;
  __shared__ f16 As[128 * 64];
  __shared__ f16 Bs[3][128 * 64];
  const int tid = threadIdx.x;
  const int lane = tid & 63, wid = tid >> 6;
  const int lq = lane & 15, lg = lane >> 4;
  const int wm = wid >> 1, wn = wid & 1;
  const int r0 = blockIdx.x * 128, c0 = blockIdx.y * 128;

  f32x4 acc[3][4][4] = {};

  for (int k0 = 0; k0 < K; k0 += 64) {
#pragma unroll
    for (int it = 0; it < 4; ++it) {
      const int off = it * 4096 + tid * 16;
      const int row = off >> 7;
      const int cb = (off >> 4) & 7;
      const int kc = k0 + ((cb ^ (row & 7)) << 3);
      const f16* src;
      if (CONCATA) {
        src = (kc < 512) ? (A + (size_t)(r0 + row) * 512 + kc)
                         : (A2 + (size_t)(r0 + row) * 512 + (kc - 512));
      } else {
        src = A + (size_t)(r0 + row) * K + kc;
      }
      gload_lds16(src, (f16*)((char*)As + off));
    }
#pragma unroll
    for (int g = 0; g < 3; ++g) {
      const int gbase = (g == 0) ? 0 : 512 * (g + 1);  // i=0, g=1024, o=1536
#pragma unroll
      for (int it = 0; it < 4; ++it) {
        const int off = it * 4096 + tid * 16;
        const int row = off >> 7;
        const int cb = (off >> 4) & 7;
        gload_lds16(
            Wih + (size_t)(gbase + c0 + row) * K + k0 + ((cb ^ (row & 7)) << 3),
            (f16*)((char*)&Bs[g][0] + off));
      }
    }
    __syncthreads();
#pragma unroll
    for (int kk = 0; kk < 2; ++kk) {
      f16x8 af[4];
#pragma unroll
      for (int m = 0; m < 4; ++m) {
        const int row = wm * 64 + m * 16 + lq;
        af[m] = *(const f16x8*)((const char*)As + row * 128 +
                                (((kk * 4 + lg) ^ (row & 7)) << 4));
      }
#pragma unroll
      for (int g = 0; g < 3; ++g)
#pragma unroll
        for (int n = 0; n < 4; ++n) {
          const int row = wn * 64 + n * 16 + lq;
          const f16x8 bf = *(const f16x8*)((const char*)&Bs[g][0] + row * 128 +
                                           (((kk * 4 + lg) ^ (row & 7)) << 4));
#pragma unroll
          for (int m = 0; m < 4; ++m)
            acc[g][m][n] = MFMA16(af[m], bf, acc[g][m][n]);
        }
    }
    __syncthreads();
  }

#pragma unroll
  for (int n = 0; n < 4; ++n) {
    const int c = c0 + wn * 64 + n * 16 + lq;
    const float bi = bih[c] + bhh[c];
    const float bg = bih[1024 + c] + bhh[1024 + c];
    const float bo = bih[1536 + c] + bhh[1536 + c];
#pragma unroll
    for (int m = 0; m < 4; ++m) {
      const int rbase = r0 + wm * 64 + m * 16 + lg * 4;
#pragma unroll
      for (int r = 0; r < 4; ++r) {
        const float gi = acc[0][m][n][r] + bi;
        const float gg = acc[1][m][n][r] + bg;
        const float go = acc[2][m][n][r] + bo;
        const float si = 1.f / (1.f + __expf(-gi));
        const float so = 1.f / (1.f + __expf(-go));
        const float tg = 2.f / (1.f + __expf(-2.f * gg)) - 1.f;
        const float cc = si * tg;
        const float tc = 2.f / (1.f + __expf(-2.f * cc)) - 1.f;
        Hout_[(size_t)(rbase + r) * 512 + c] = (f16)(so * tc);
      }
    }
  }
}

// ---------------------------------------------------------------------------
// Flash attention v7 [validated R15]
// ---------------------------------------------------------------------------
__global__ __launch_bounds__(256, 4) void attn_mfma7(
    const f16* __restrict__ q, const f16* __restrict__ k,
    const f16* __restrict__ vT, f16* __restrict__ ctx) {
  __shared__ f16 Ks[2][64 * 64];
  __shared__ f16 Vs[2][64 * 64];
  __shared__ f16 Ps[4][16 * 64];
  const int bid = blockIdx.x;
  const int nid = (bid & 7) * 128 + (bid >> 3);
  const int qt = nid & 7, bh = nid >> 3;
  const int head = bh & 7, b = bh >> 3;
  const int tid = threadIdx.x, lane = tid & 63, wid = tid >> 6;
  const int lq = lane & 15, lg = lane >> 4;

  const f16* kbase = k + ((size_t)b * T_) * H_ + head * D_;
  const f16* vbase = vT + (size_t)bh * D_ * T_;

  auto stage = [&](int kt, int buf) {
#pragma unroll
    for (int it = 0; it < 2; ++it) {
      const int off = it * 4096 + tid * 16;
      const int row = off >> 7;
      const int sc = ((((off >> 4) & 7) ^ (row & 7)) << 3);
      gload_lds16(kbase + (size_t)(kt * 64 + row) * H_ + sc,
                  (f16*)((char*)&Ks[buf][0] + off));
      gload_lds16(vbase + (size_t)row * T_ + kt * 64 + sc,
                  (f16*)((char*)&Vs[buf][0] + off));
    }
  };

  const int q0 = qt * 128 + wid * 32;
  f16x8 qf[2][2];
#pragma unroll
  for (int s = 0; s < 2; ++s)
#pragma unroll
    for (int kk = 0; kk < 2; ++kk)
      qf[s][kk] = *(const f16x8*)(q + ((size_t)(b * T_) + q0 + s * 16 + lq) * H_ +
                                  head * D_ + kk * 32 + lg * 8);

  f16x8 ones;
#pragma unroll
  for (int j = 0; j < 8; ++j) ones[j] = (f16)1.f;

  f32x4 accO[2][4] = {};
  f32x4 accL[2] = {};
  char* pw = (char*)&Ps[wid][0] + lq * 128;
  const int psw = (lq & 7) << 4;

  stage(0, 0);
  __syncthreads();

  for (int kt = 0; kt < T_ / 64; ++kt) {
    const int cur = kt & 1;
    if (kt < T_ / 64 - 1) stage(kt + 1, cur ^ 1);

    f16x8 kf[4][2];
#pragma unroll
    for (int n = 0; n < 4; ++n)
#pragma unroll
      for (int kk = 0; kk < 2; ++kk) {
        const int row = n * 16 + lq;
        kf[n][kk] = *(const f16x8*)((const char*)&Ks[cur][0] + row * 128 +
                                    (((kk * 4 + lg) ^ (row & 7)) << 4));
      }

#pragma unroll
    for (int s = 0; s < 2; ++s) {
      f32x4 ssw[4] = {};
      __builtin_amdgcn_s_setprio(1);
#pragma unroll
      for (int n = 0; n < 4; ++n)
#pragma unroll
        for (int kk = 0; kk < 2; ++kk)
          ssw[n] = MFMA16(kf[n][kk], qf[s][kk], ssw[n]);
      __builtin_amdgcn_s_setprio(0);

#pragma unroll
      for (int n = 0; n < 4; ++n) {
        f16x4 pk;
#pragma unroll
        for (int r = 0; r < 4; ++r) pk[r] = (f16)fexp2(ssw[n][r]);
        *(f16x4*)(pw + ((n * 32 + lg * 8) ^ psw)) = pk;
      }
      f16x8 pb[2];
#pragma unroll
      for (int kk = 0; kk < 2; ++kk)
        pb[kk] = *(const f16x8*)(pw + ((((kk * 4 + lg) << 4)) ^ psw));

      __builtin_amdgcn_s_setprio(1);
#pragma unroll
      for (int kk = 0; kk < 2; ++kk)
        accL[s] = MFMA16(ones, pb[kk], accL[s]);
#pragma unroll
      for (int n = 0; n < 4; ++n) {
        const int row = n * 16 + lq;
#pragma unroll
        for (int kk = 0; kk < 2; ++kk) {
          const f16x8 vf =
              *(const f16x8*)((const char*)&Vs[cur][0] + row * 128 +
                              (((kk * 4 + lg) ^ (row & 7)) << 4));
          accO[s][n] = MFMA16(vf, pb[kk], accO[s][n]);
        }
      }
      __builtin_amdgcn_s_setprio(0);
    }
    __syncthreads();
  }

#pragma unroll
  for (int s = 0; s < 2; ++s) {
    const float inv = 1.f / accL[s][0];
    const size_t rowoff = ((size_t)(b * T_) + q0 + s * 16 + lq) * H_ + head * D_;
#pragma unroll
    for (int n = 0; n < 4; ++n) {
      f16x4 o;
#pragma unroll
      for (int r = 0; r < 4; ++r) o[r] = (f16)(accO[s][n][r] * inv);
      *(f16x4*)(ctx + rowoff + n * 16 + lg * 4) = o;
    }
  }
}

// ---------------------------------------------------------------------------
// Merged conversions + builders [validated R7-R15]
// ---------------------------------------------------------------------------
constexpr int C0 = 2097152;            // enc
constexpr int C1 = C0 + 196608;        // inw
constexpr int C2 = C1 + 65536;         // outw
constexpr int C3 = C2 + 524288;        // wih0
constexpr int C4 = C3 + 262144;        // wih1
constexpr int C5 = C4 + 10240;         // wmel
constexpr int C6 = C5 + 524288;        // pm
constexpr int C7 = C6 + 16384;         // wp
__global__ void conv_all(const float* __restrict__ enc, const float* __restrict__ inw,
                         const float* __restrict__ outw, const float* __restrict__ wih0,
                         const float* __restrict__ wih1, const float* __restrict__ wmel,
                         const float* __restrict__ tmel, const float* __restrict__ wpre,
                         f16* denc, f16* dinw, f16* doutw, f16* dwih0,
                         f16* dwih1, f16* dwmel, f16* dpm, f16* dwp) {
  const int i = blockIdx.x * blockDim.x + threadIdx.x;
  if (i >= C7) return;
  if (i < C5) {
    const float* s;
    f16* d;
    int off;
    if (i < C0) { s = enc; d = denc; off = i; }
    else if (i < C1) { s = inw; d = dinw; off = i - C0; }
    else if (i < C2) { s = outw; d = doutw; off = i - C1; }
    else if (i < C3) { s = wih0; d = dwih0; off = i - C2; }
    else if (i < C4) { s = wih1; d = dwih1; off = i - C3; }
    else { s = wmel; d = dwmel; off = i - C4; }
    const float4 v = ((const float4*)s)[off];
    f16x4 o = {(f16)v.x, (f16)v.y, (f16)v.z, (f16)v.w};
    ((f16x4*)d)[off] = o;
  } else if (i < C6) {
    const int j = i - C5;
    const int r = j >> 5, c4 = (j & 31) * 4;
    const int t = r & (T_ - 1);
    f16x4 o = {};
    if (t != 0 && c4 < M_) {
      const float4 v = *(const float4*)(tmel + (size_t)(r - 1) * M_ + c4);
      o = {(f16)v.x, (f16)v.y, (f16)v.z, (f16)v.w};
    }
    *(f16x4*)(dpm + (size_t)r * 128 + c4) = o;
  } else {
    const int j = i - C6;
    const int r = j >> 5, c4 = (j & 31) * 4;
    f16x4 o = {};
    if (c4 < M_) {
      const float4 v = *(const float4*)(wpre + (size_t)r * M_ + c4);
      o = {(f16)v.x, (f16)v.y, (f16)v.z, (f16)v.w};
    }
    *(f16x4*)(dwp + (size_t)r * 128 + c4) = o;
  }
}

// ---------------------------------------------------------------------------
extern "C" void kernel_launch(void* const* d_in, const int* in_sizes, int n_in,
                              void* d_out, int out_size, void* d_ws,
                              size_t ws_size, hipStream_t stream) {
  const float* enc = (const float*)d_in[0];
  const float* tmel = (const float*)d_in[1];
  const float* w_pre = (const float*)d_in[2];
  const float* b_pre = (const float*)d_in[3];
  const float* inw = (const float*)d_in[4];
  const float* inb = (const float*)d_in[5];
  const float* outw = (const float*)d_in[6];
  const float* outb = (const float*)d_in[7];
  const float* wih0 = (const float*)d_in[8];
  const float* bih0 = (const float*)d_in[10];
  const float* bhh0 = (const float*)d_in[11];
  const float* wih1 = (const float*)d_in[12];
  const float* bih1 = (const float*)d_in[14];
  const float* bhh1 = (const float*)d_in[15];
  const float* wmel = (const float*)d_in[16];
  const float* bmel = (const float*)d_in[17];

  f16* wsh = (f16*)d_ws;
  const size_t SEG = (size_t)N_ * H_;
  f16* EncB = wsh;                     // S0; reused as aout
  f16* h1 = wsh + SEG;                 // S1
  f16* pre = wsh + 2 * SEG;            // S2
  f16* qb = wsh + 3 * SEG;             // S3; reused as h2
  f16* kbuf = wsh + 4 * SEG;           // S4
  f16* vTb = wsh + 5 * SEG;            // S5
  f16* ctx = wsh + 6 * SEG;            // S6
  f16* aout = EncB;
  f16* h2 = qb;
  f16* WP = wsh + 7 * SEG;
  f16* WIN = WP + 512 * 128;
  f16* WOUT = WIN + 1536 * 512;
  f16* WIH0 = WOUT + 512 * 512;
  f16* WIH1 = WIH0 + (size_t)2048 * 1024;
  f16* WMEL = WIH1 + 2048 * 512;
  f16* PM = WMEL + 80 * 512;

  const dim3 blk(256);
  conv_all<<<(C7 + 255) / 256, blk, 0, stream>>>(
      enc, inw, outw, wih0, wih1, wmel, tmel, w_pre, EncB, WIN, WOUT, WIH0,
      WIH1, WMEL, PM, WP);

  // prenet || kv projection
  prenet_kv<<<dim3(1024), blk, 0, stream>>>(PM, WP, b_pre, pre, EncB,
                                            WIN + 512 * 512, inb + 512, kbuf,
                                            vTb);

  const dim3 g512(N_ / 128, 4), g80(N_ / 128, 1);
  // q pre-scaled by log2e / sqrt(64) -> softmax runs in exp2 domain
  mgemm<0, false, false><<<g512, blk, 0, stream>>>(
      pre, nullptr, WIN, inb, nullptr, 0.125f * 1.44269504088896f, qb, 512, 512);
  attn_mfma7<<<dim3(1024), blk, 0, stream>>>(qb, kbuf, vTb, ctx);
  mgemm<0, false, false><<<g512, blk, 0, stream>>>(ctx, nullptr, WOUT, outb,
                                                   nullptr, 1.f, aout, 512, 512);
  lstm_fused<true><<<g512, blk, 0, stream>>>(pre, aout, WIH0, bih0, bhh0, h1);
  lstm_fused<false><<<g512, blk, 0, stream>>>(h1, nullptr, WIH1, bih1, bhh1, h2);
  mgemm<4, false, true><<<g80, blk, 0, stream>>>(h2, nullptr, WMEL, bmel,
                                                 nullptr, 1.f, (float*)d_out,
                                                 512, 80);
}